// Round 9
// baseline (43.313 us; speedup 1.0000x reference)
//
#include <hip/hip_runtime.h>

// GridMatch: A=8, B=8, N=2048, grid 640x480 per (a,b) image.
// Single fused kernel. Only the 64 per-image match COUNTS cross blocks
// (via device-scope atomics, hardware-coherent). Records stay in LDS of
// the block that produced them; that block emits its own image's rows.
// Fill blocks pad rows >= n only (disjoint from emitted rows [0,n)).
#define AD 8
#define BD 8
#define NP 2048
#define MPTS (AD*BD*NP)            // 131072 points
#define NIMG (AD*BD)               // 64 images
#define HSZ 4096                   // LDS hash slots (>= max distinct cells/image)
#define RCAP 2048                  // max matches/image (<= #src cells <= 2048)
#define NBLK 256                   // 64 hash+emit blocks + 192 fill blocks

__device__ int g_cnt[NIMG];        // per-image match count (atomics only)
__device__ int g_pub;              // #published counts; reset by last acker
__device__ int g_ack;              // #blocks done reading; reset by last acker

#define ALOAD(p)     __hip_atomic_load((p), __ATOMIC_ACQUIRE, __HIP_MEMORY_SCOPE_AGENT)
#define ASTORE(p, v) __hip_atomic_store((p), (v), __ATOMIC_RELAXED, __HIP_MEMORY_SCOPE_AGENT)

__global__ __launch_bounds__(256) void k_fused(
    const float* __restrict__ ps, const float* __restrict__ pd,
    float* __restrict__ out,
    const int* __restrict__ ph, const int* __restrict__ pw,
    const int* __restrict__ pg) {
  __shared__ int hkey[HSZ];
  __shared__ int hsrc[HSZ];
  __shared__ int hdst[HSZ];
  __shared__ int lrc[RCAP];        // this image's records (LDS-resident)
  __shared__ int lrs[RCAP];
  __shared__ int lrd[RCAP];
  __shared__ int lcnt;
  __shared__ int scnt[NIMG];
  __shared__ int sbase;            // emit: soff[b]; fill: n

  int b = blockIdx.x, tid = threadIdx.x;
  int h = *ph, w = *pw, gs = *pg;
  int gh = h * gs, gw = w * gs;
  float sx = (float)((gw - 1) * 0.5);
  float sy = (float)((gh - 1) * 0.5);

  if (b < NIMG) {
    // ================= hash + publish + emit-own-image =================
    for (int i = tid; i < HSZ; i += 256) { hkey[i] = -1; hsrc[i] = 0; hdst[i] = 0; }
    if (tid == 0) lcnt = 0;
    __syncthreads();

    auto insert = [&](float px, float py, int gid, int* field) {
      if (!(px >= -1.f && px <= 1.f && py >= -1.f && py <= 1.f)) return;
      int c = (int)((px + 1.f) * sx) * gh + (int)((py + 1.f) * sy);  // local row-major
      int i = (int)(((unsigned)c * 2654435761u) >> 20) & (HSZ - 1);
      while (true) {
        int k = atomicCAS(&hkey[i], -1, c);
        if (k == -1 || k == c) { atomicMax(&field[i], gid + 1); return; }
        i = (i + 1) & (HSZ - 1);
      }
    };

    const float4* sp = (const float4*)ps + b * (NP/2);
    const float4* dp = (const float4*)pd + b * (NP/2);
    int gbase = b * NP;
#pragma unroll
    for (int k = 0; k < NP/512; ++k) {       // 4 x 256 float4 = 2048 pts/side
      int f = k*256 + tid;
      float4 s2 = sp[f];
      insert(s2.x, s2.y, gbase + 2*f,     hsrc);
      insert(s2.z, s2.w, gbase + 2*f + 1, hsrc);
      float4 d2 = dp[f];
      insert(d2.x, d2.y, gbase + 2*f,     hdst);
      insert(d2.z, d2.w, gbase + 2*f + 1, hdst);
    }
    __syncthreads();

    for (int i = tid; i < HSZ; i += 256) {   // records -> LDS only
      if (hkey[i] >= 0) {
        int s = hsrc[i], d = hdst[i];
        if (s > 0 && d > 0) {
          int slot = atomicAdd(&lcnt, 1);
          lrc[slot] = hkey[i];
          lrs[slot] = s - 1;
          lrd[slot] = d - 1;
        }
      }
    }
    __syncthreads();

    if (tid == 0) {
      ASTORE(&g_cnt[b], lcnt);               // publish count...
      __hip_atomic_fetch_add(&g_pub, 1, __ATOMIC_RELEASE, __HIP_MEMORY_SCOPE_AGENT);
      while (ALOAD(&g_pub) < NIMG) __builtin_amdgcn_s_sleep(2);   // ...await peers
    }
    __syncthreads();
    if (tid < NIMG) scnt[tid] = ALOAD(&g_cnt[tid]);
    __syncthreads();
    if (tid == 0) {
      int acc = 0;
      for (int i = 0; i < b; ++i) acc += scnt[i];
      sbase = acc;                           // this image's global rank offset
    }
    __syncthreads();

    int cnt = lcnt, soff = sbase;
    float fxm = (float)((double)(h - 1) / (double)(gh - 1));  // pairs with x (faithful)
    float fym = (float)((double)(w - 1) / (double)(gw - 1));
    float* out0 = out;
    float* out1 = out + 2*MPTS;
    float* out2 = out + 4*MPTS;
    float* out3 = out + 6*MPTS;
    float* out4 = out + 8*MPTS;
    for (int j = tid; j < cnt; j += 256) {
      int ci = lrc[j];
      int rank = soff;
      for (int i = 0; i < cnt; ++i) rank += (int)(lrc[i] < ci);  // cells unique
      int s = lrs[j], d = lrd[j];
      float2 a2 = ((const float2*)ps)[s];
      out0[2*rank]   = (a2.x + 1.f) * sx * fxm;
      out0[2*rank+1] = (a2.y + 1.f) * sy * fym;
      float2 b2 = ((const float2*)pd)[d];
      out1[2*rank]   = (b2.x + 1.f) * sx * fxm;
      out1[2*rank+1] = (b2.y + 1.f) * sy * fym;
      out2[2*rank]   = (float)((s / NP) % BD);
      out2[2*rank+1] = (float)(s % NP);
      out3[2*rank]   = (float)(d / (BD * NP));
      out3[2*rank+1] = (float)(d % NP);
      out4[rank]     = 1.f;
    }
  } else {
    // ================= fill blocks: pad rows >= n only =================
    if (tid == 0) {
      while (ALOAD(&g_pub) < NIMG) __builtin_amdgcn_s_sleep(2);
    }
    __syncthreads();
    if (tid < NIMG) scnt[tid] = ALOAD(&g_cnt[tid]);
    __syncthreads();
    if (tid == 0) {
      int acc = 0;
      for (int i = 0; i < NIMG; ++i) acc += scnt[i];
      sbase = acc;                           // n = total matches
    }
    __syncthreads();
    int n = sbase;

    // flat float4 space: q in [0,294912). q<262144: arrays out0..3
    // (arr = q>>16, rows {2*ql, 2*ql+1}); else valid (rows 4*qv..4*qv+3).
    const float4 z4  = make_float4(0.f, 0.f, 0.f, 0.f);
    const float4 m14 = make_float4(-1.f, -1.f, -1.f, -1.f);
    float4* o4 = (float4*)out;
    int pb = b - NIMG;                       // 0..191
#pragma unroll
    for (int k = 0; k < 6; ++k) {            // 192*256*6 = 294912 float4 exactly
      int q = (pb*6 + k)*256 + tid;
      if (q < 262144) {
        int arr = q >> 16, ql = q & 65535, r0 = 2*ql;
        float4 v4 = (arr < 2) ? z4 : m14;
        if (r0 >= n) {
          o4[q] = v4;
        } else if (r0 + 1 >= n) {            // boundary: pad row r0+1 only
          ((float2*)out)[2*q + 1] = (arr < 2) ? make_float2(0.f, 0.f)
                                              : make_float2(-1.f, -1.f);
        }
      } else {
        int qv = q - 262144, r0 = 4*qv;
        if (r0 >= n) {
          o4[q] = z4;
        } else if (r0 + 3 >= n) {            // boundary: pad rows >= n
          for (int r = r0; r < r0 + 4; ++r)
            if (r >= n) out[8*MPTS + r] = 0.f;
        }
      }
    }
  }

  // ---- ack; 256th acker resets the cross-call flags (nobody waits) ----
  __syncthreads();
  if (tid == 0) {
    int a = __hip_atomic_fetch_add(&g_ack, 1, __ATOMIC_ACQ_REL, __HIP_MEMORY_SCOPE_AGENT);
    if (a == NBLK - 1) {
      ASTORE(&g_pub, 0);
      ASTORE(&g_ack, 0);
    }
  }
}

extern "C" void kernel_launch(void* const* d_in, const int* in_sizes, int n_in,
                              void* d_out, int out_size, void* d_ws, size_t ws_size,
                              hipStream_t stream) {
  const float* ps = (const float*)d_in[0];
  const float* pd = (const float*)d_in[1];
  const int* ph = (const int*)d_in[2];
  const int* pw = (const int*)d_in[3];
  const int* pg = (const int*)d_in[4];
  float* out = (float*)d_out;

  k_fused<<<NBLK, 256, 0, stream>>>(ps, pd, out, ph, pw, pg);
}

// Round 10
// 22.557 us; speedup vs baseline: 1.9202x; 1.9202x over previous
//
#include <hip/hip_runtime.h>

// GridMatch: A=8, B=8, N=2048, grid 640x480 per (a,b) image.
// Single fused kernel, RELAXED-only atomics (rocPRIM-lookback style):
//  - 64 hash blocks: LDS hash own image -> publish count (cnt+1) -> poll all
//    64 counts (one per thread) -> emit own image's rows + pad [n, SPLIT).
//  - 192 fill blocks: sync-free static pad of rows [SPLIT, M), overlapping.
// No acquire/release/fences: only the 64 counts cross blocks, as atomic
// payloads; records stay in producer LDS.
#define AD 8
#define BD 8
#define NP 2048
#define MPTS (AD*BD*NP)            // 131072 points
#define NIMG (AD*BD)               // 64 images
#define HSZ 4096                   // LDS hash slots (>= max distinct cells/image)
#define RCAP 2048                  // max matches/image
#define SPLIT 16384                // static/dynamic padding boundary (n ~190 << SPLIT)
#define NBLK 256                   // 64 hash/emit + 192 fill

__device__ int g_cnt[NIMG];        // cnt+1; 0 = unpublished. Reset by last acker.
__device__ int g_ack;              // consumed-acks; reset by last acker.

#define ALD(p)    __hip_atomic_load((p), __ATOMIC_RELAXED, __HIP_MEMORY_SCOPE_AGENT)
#define AST(p, v) __hip_atomic_store((p), (v), __ATOMIC_RELAXED, __HIP_MEMORY_SCOPE_AGENT)

__global__ __launch_bounds__(256) void k_fused(
    const float* __restrict__ ps, const float* __restrict__ pd,
    float* __restrict__ out,
    const int* __restrict__ ph, const int* __restrict__ pw,
    const int* __restrict__ pg) {
  __shared__ int hkey[HSZ];
  __shared__ int hsrc[HSZ];
  __shared__ int hdst[HSZ];
  __shared__ int lrc[RCAP];        // this image's records (LDS-resident)
  __shared__ int lrs[RCAP];
  __shared__ int lrd[RCAP];
  __shared__ int lcnt;
  __shared__ int scnt[NIMG];
  __shared__ int s_off, s_n;

  int b = blockIdx.x, tid = threadIdx.x;
  int h = *ph, w = *pw, gs = *pg;
  int gh = h * gs, gw = w * gs;
  float sx = (float)((gw - 1) * 0.5);
  float sy = (float)((gh - 1) * 0.5);

  if (b < NIMG) {
    // ---------------- hash own image in LDS (starts immediately) ----------------
    for (int i = tid; i < HSZ; i += 256) { hkey[i] = -1; hsrc[i] = 0; hdst[i] = 0; }
    if (tid == 0) lcnt = 0;
    __syncthreads();

    auto insert = [&](float px, float py, int gid, int* field) {
      if (!(px >= -1.f && px <= 1.f && py >= -1.f && py <= 1.f)) return;
      int c = (int)((px + 1.f) * sx) * gh + (int)((py + 1.f) * sy);  // local row-major
      int i = (int)(((unsigned)c * 2654435761u) >> 20) & (HSZ - 1);
      while (true) {
        int k = atomicCAS(&hkey[i], -1, c);
        if (k == -1 || k == c) { atomicMax(&field[i], gid + 1); return; }
        i = (i + 1) & (HSZ - 1);
      }
    };

    const float4* sp = (const float4*)ps + b * (NP/2);
    const float4* dp = (const float4*)pd + b * (NP/2);
    int gbase = b * NP;
#pragma unroll
    for (int k = 0; k < NP/512; ++k) {       // 4 x 256 float4 = 2048 pts/side
      int f = k*256 + tid;
      float4 s2 = sp[f];
      insert(s2.x, s2.y, gbase + 2*f,     hsrc);
      insert(s2.z, s2.w, gbase + 2*f + 1, hsrc);
      float4 d2 = dp[f];
      insert(d2.x, d2.y, gbase + 2*f,     hdst);
      insert(d2.z, d2.w, gbase + 2*f + 1, hdst);
    }
    __syncthreads();

    for (int i = tid; i < HSZ; i += 256) {   // records -> LDS only
      if (hkey[i] >= 0) {
        int s = hsrc[i], d = hdst[i];
        if (s > 0 && d > 0) {
          int slot = atomicAdd(&lcnt, 1);
          lrc[slot] = hkey[i];
          lrs[slot] = s - 1;
          lrd[slot] = d - 1;
        }
      }
    }
    __syncthreads();

    // ---------------- publish count; poll peers (1 count per thread) ----------------
    if (tid == 0) AST(&g_cnt[b], lcnt + 1);
    if (tid < NIMG) {
      int v;
      while ((v = ALD(&g_cnt[tid])) == 0) __builtin_amdgcn_s_sleep(1);
      scnt[tid] = v - 1;
    }
    __syncthreads();
    if (tid == 0) {
      int acc = 0, tot = 0;
      for (int i = 0; i < NIMG; ++i) { if (i < b) acc += scnt[i]; tot += scnt[i]; }
      s_off = acc; s_n = tot;
      // ack; the 64th acker resets the flags (all consumers hold LDS copies)
      int old = __hip_atomic_fetch_add(&g_ack, 1, __ATOMIC_RELAXED, __HIP_MEMORY_SCOPE_AGENT);
      if (old == NIMG - 1) {
        for (int i = 0; i < NIMG; ++i) AST(&g_cnt[i], 0);
        AST(&g_ack, 0);
      }
    }
    __syncthreads();

    // ---------------- emit own image's rows at global ranks ----------------
    int cnt = lcnt, soff = s_off, n = s_n;
    float fxm = (float)((double)(h - 1) / (double)(gh - 1));  // pairs with x (faithful)
    float fym = (float)((double)(w - 1) / (double)(gw - 1));
    float* out0 = out;
    float* out1 = out + 2*MPTS;
    float* out2 = out + 4*MPTS;
    float* out3 = out + 6*MPTS;
    float* out4 = out + 8*MPTS;
    for (int j = tid; j < cnt; j += 256) {
      int ci = lrc[j];
      int rank = soff;
      for (int i = 0; i < cnt; ++i) rank += (int)(lrc[i] < ci);  // cells unique
      int s = lrs[j], d = lrd[j];
      float2 a2 = ((const float2*)ps)[s];
      out0[2*rank]   = (a2.x + 1.f) * sx * fxm;
      out0[2*rank+1] = (a2.y + 1.f) * sy * fym;
      float2 b2 = ((const float2*)pd)[d];
      out1[2*rank]   = (b2.x + 1.f) * sx * fxm;
      out1[2*rank+1] = (b2.y + 1.f) * sy * fym;
      out2[2*rank]   = (float)((s / NP) % BD);
      out2[2*rank+1] = (float)(s % NP);
      out3[2*rank]   = (float)(d / (BD * NP));
      out3[2*rank+1] = (float)(d % NP);
      out4[rank]     = 1.f;
    }

    // ---------------- dynamic pad: rows [n, SPLIT), 64x256 = 16384 slots ----------------
    {
      int rr = n + b*256 + tid;              // covers [n, n+16384) >= [n, SPLIT)
      if (rr < SPLIT) {
        float2* o2 = (float2*)out;
        o2[rr]          = make_float2(0.f, 0.f);
        o2[MPTS + rr]   = make_float2(0.f, 0.f);
        o2[2*MPTS + rr] = make_float2(-1.f, -1.f);
        o2[3*MPTS + rr] = make_float2(-1.f, -1.f);
        out[8*MPTS + rr] = 0.f;
      }
    }
  } else {
    // ---------------- fill blocks: static pad rows [SPLIT, M), sync-free ----------------
    // 4 arrays x (MPTS-SPLIT)/2 = 229376 float4, + valid (MPTS-SPLIT)/4 = 28672
    // -> 258048 float4 = 192 blocks x 1344.
    const float4 z4  = make_float4(0.f, 0.f, 0.f, 0.f);
    const float4 m14 = make_float4(-1.f, -1.f, -1.f, -1.f);
    float4* o4 = (float4*)out;
    int pb = b - NIMG;                       // 0..191
#pragma unroll
    for (int k = 0; k < 6; ++k) {
      int u = k*256 + tid;
      if (u < 1344) {
        int q = pb*1344 + u;
        if (q < 229376) {
          int arr = q / 57344, idx = q % 57344;
          o4[arr*(MPTS/2) + SPLIT/2 + idx] = (arr < 2) ? z4 : m14;
        } else {
          int qv = q - 229376;
          o4[2*MPTS + SPLIT/4 + qv] = z4;    // valid: float4 base 8*MPTS/4 = 2*MPTS
        }
      }
    }
  }
}

extern "C" void kernel_launch(void* const* d_in, const int* in_sizes, int n_in,
                              void* d_out, int out_size, void* d_ws, size_t ws_size,
                              hipStream_t stream) {
  const float* ps = (const float*)d_in[0];
  const float* pd = (const float*)d_in[1];
  const int* ph = (const int*)d_in[2];
  const int* pw = (const int*)d_in[3];
  const int* pg = (const int*)d_in[4];
  float* out = (float*)d_out;

  k_fused<<<NBLK, 256, 0, stream>>>(ps, pd, out, ph, pw, pg);
}

// Round 11
// 21.646 us; speedup vs baseline: 2.0010x; 1.0421x over previous
//
#include <hip/hip_runtime.h>

// GridMatch: A=8, B=8, N=2048, grid 640x480 per (a,b) image.
// Two kernels, zero fences/atomics across blocks (kernel boundary = sync):
//  k1: blocks 0-63 pure per-image LDS hash (records -> global, tiny);
//      blocks 64-255 static pad of rows [SPLIT, M) concurrently.
//  k2: 64 blocks; plain-load counts, prefix in LDS, emit own image's rows,
//      dynamic pad [n, min(n+16384, SPLIT)). Correct for any n (emit
//      overwrites k1 padding where they overlap, ordered by the boundary).
#define AD 8
#define BD 8
#define NP 2048
#define MPTS (AD*BD*NP)            // 131072 points
#define NIMG (AD*BD)               // 64 images
#define HSZ 4096                   // LDS hash slots (>= max distinct cells/image)
#define RCAP 2048                  // max matches/image
#define SPLIT 16384                // static/dynamic padding boundary

// Fully rewritten every call (no cross-call invariants, no resets needed).
__device__ int g_cnt[NIMG];
__device__ int g_rc[NIMG*RCAP];    // local cell index (x*gh + y) — rank key
__device__ int g_rs[NIMG*RCAP];    // global src point id
__device__ int g_rd[NIMG*RCAP];    // global dst point id

// ---- k1: 64 pure-hash blocks + 192 static-fill blocks ----
__global__ __launch_bounds__(256) void k_hash(
    const float* __restrict__ ps, const float* __restrict__ pd,
    float* __restrict__ out,
    const int* __restrict__ ph, const int* __restrict__ pw,
    const int* __restrict__ pg) {
  __shared__ int hkey[HSZ];
  __shared__ int hsrc[HSZ];
  __shared__ int hdst[HSZ];
  __shared__ int lcnt;

  int b = blockIdx.x, tid = threadIdx.x;

  if (b >= NIMG) {
    // ---- static pad rows [SPLIT, M): 4 arrays x 57344 + valid 28672
    // = 258048 float4 = 192 blocks x 1344 ----
    const float4 z4  = make_float4(0.f, 0.f, 0.f, 0.f);
    const float4 m14 = make_float4(-1.f, -1.f, -1.f, -1.f);
    float4* o4 = (float4*)out;
    int pb = b - NIMG;                       // 0..191
#pragma unroll
    for (int k = 0; k < 6; ++k) {
      int u = k*256 + tid;
      if (u < 1344) {
        int q = pb*1344 + u;
        if (q < 229376) {
          int arr = q / 57344, idx = q % 57344;
          o4[arr*(MPTS/2) + SPLIT/2 + idx] = (arr < 2) ? z4 : m14;
        } else {
          int qv = q - 229376;
          o4[2*MPTS + SPLIT/4 + qv] = z4;    // valid: float4 base 8*MPTS/4
        }
      }
    }
    return;
  }

  // ---- hash own image in LDS (no fill prelude: starts immediately) ----
  for (int i = tid; i < HSZ; i += 256) { hkey[i] = -1; hsrc[i] = 0; hdst[i] = 0; }
  if (tid == 0) lcnt = 0;
  __syncthreads();

  int h = *ph, w = *pw, gs = *pg;
  int gh = h * gs, gw = w * gs;
  float sx = (float)((gw - 1) * 0.5);
  float sy = (float)((gh - 1) * 0.5);

  auto insert = [&](float px, float py, int gid, int* field) {
    if (!(px >= -1.f && px <= 1.f && py >= -1.f && py <= 1.f)) return;
    int c = (int)((px + 1.f) * sx) * gh + (int)((py + 1.f) * sy);  // local row-major
    int i = (int)(((unsigned)c * 2654435761u) >> 20) & (HSZ - 1);
    while (true) {
      int k = atomicCAS(&hkey[i], -1, c);
      if (k == -1 || k == c) { atomicMax(&field[i], gid + 1); return; }
      i = (i + 1) & (HSZ - 1);
    }
  };

  const float4* sp = (const float4*)ps + b * (NP/2);
  const float4* dp = (const float4*)pd + b * (NP/2);
  int gbase = b * NP;
#pragma unroll
  for (int k = 0; k < NP/512; ++k) {         // 4 x 256 float4 = 2048 pts/side
    int f = k*256 + tid;
    float4 s2 = sp[f];
    insert(s2.x, s2.y, gbase + 2*f,     hsrc);
    insert(s2.z, s2.w, gbase + 2*f + 1, hsrc);
    float4 d2 = dp[f];
    insert(d2.x, d2.y, gbase + 2*f,     hdst);
    insert(d2.z, d2.w, gbase + 2*f + 1, hdst);
  }
  __syncthreads();

  // cells holding both a src and a dst winner -> record (global, tiny)
  for (int i = tid; i < HSZ; i += 256) {
    if (hkey[i] >= 0) {
      int s = hsrc[i], d = hdst[i];
      if (s > 0 && d > 0) {
        int slot = atomicAdd(&lcnt, 1);
        g_rc[b*RCAP + slot] = hkey[i];
        g_rs[b*RCAP + slot] = s - 1;
        g_rd[b*RCAP + slot] = d - 1;
      }
    }
  }
  __syncthreads();
  if (tid == 0) g_cnt[b] = lcnt;
}

// ---- k2: 64 blocks; prefix counts, emit own image, dynamic pad [n, SPLIT) ----
__global__ __launch_bounds__(256) void k_emit(
    const float* __restrict__ ps, const float* __restrict__ pd,
    float* __restrict__ out,
    const int* __restrict__ ph, const int* __restrict__ pw,
    const int* __restrict__ pg) {
  __shared__ int scnt[NIMG];
  __shared__ int s_off, s_n;
  int b = blockIdx.x, tid = threadIdx.x;
  if (tid < NIMG) scnt[tid] = g_cnt[tid];    // plain loads (boundary-coherent)
  __syncthreads();
  if (tid == 0) {
    int acc = 0, tot = 0;
    for (int i = 0; i < NIMG; ++i) { if (i < b) acc += scnt[i]; tot += scnt[i]; }
    s_off = acc; s_n = tot;
  }
  __syncthreads();

  int cnt = scnt[b], soff = s_off, n = s_n;

  int h = *ph, w = *pw, gs = *pg;
  int gh = h * gs, gw = w * gs;
  float sx = (float)((gw - 1) * 0.5);
  float sy = (float)((gh - 1) * 0.5);
  float fxm = (float)((double)(h - 1) / (double)(gh - 1));  // pairs with x (faithful)
  float fym = (float)((double)(w - 1) / (double)(gw - 1));

  float* out0 = out;               // src_coord_m [M,2]
  float* out1 = out + 2*MPTS;      // dst_coord_m [M,2]
  float* out2 = out + 4*MPTS;      // src_bn      [M,2]
  float* out3 = out + 6*MPTS;      // dst_an      [M,2]
  float* out4 = out + 8*MPTS;      // valid       [M]

  for (int j = tid; j < cnt; j += 256) {
    int ci = g_rc[b*RCAP + j];
    int rank = soff;
    for (int i = 0; i < cnt; ++i) rank += (int)(g_rc[b*RCAP + i] < ci);  // cells unique
    int s = g_rs[b*RCAP + j], d = g_rd[b*RCAP + j];
    float2 a2 = ((const float2*)ps)[s];
    out0[2*rank]   = (a2.x + 1.f) * sx * fxm;
    out0[2*rank+1] = (a2.y + 1.f) * sy * fym;
    float2 b2 = ((const float2*)pd)[d];
    out1[2*rank]   = (b2.x + 1.f) * sx * fxm;
    out1[2*rank+1] = (b2.y + 1.f) * sy * fym;
    out2[2*rank]   = (float)((s / NP) % BD);
    out2[2*rank+1] = (float)(s % NP);
    out3[2*rank]   = (float)(d / (BD * NP));
    out3[2*rank+1] = (float)(d % NP);
    out4[rank]     = 1.f;
  }

  // dynamic pad: rows [n, n+16384) clamped to SPLIT (covers [n, SPLIT))
  int rr = n + b*256 + tid;
  if (rr < SPLIT) {
    float2* o2 = (float2*)out;
    o2[rr]          = make_float2(0.f, 0.f);
    o2[MPTS + rr]   = make_float2(0.f, 0.f);
    o2[2*MPTS + rr] = make_float2(-1.f, -1.f);
    o2[3*MPTS + rr] = make_float2(-1.f, -1.f);
    out[8*MPTS + rr] = 0.f;
  }
}

extern "C" void kernel_launch(void* const* d_in, const int* in_sizes, int n_in,
                              void* d_out, int out_size, void* d_ws, size_t ws_size,
                              hipStream_t stream) {
  const float* ps = (const float*)d_in[0];
  const float* pd = (const float*)d_in[1];
  const int* ph = (const int*)d_in[2];
  const int* pw = (const int*)d_in[3];
  const int* pg = (const int*)d_in[4];
  float* out = (float*)d_out;

  k_hash<<<256,  256, 0, stream>>>(ps, pd, out, ph, pw, pg);
  k_emit<<<NIMG, 256, 0, stream>>>(ps, pd, out, ph, pw, pg);
}

// Round 12
// 16.860 us; speedup vs baseline: 2.5690x; 1.2839x over previous
//
#include <hip/hip_runtime.h>

// GridMatch: A=8, B=8, N=2048, grid 640x480 per (a,b) image.
// Two kernels; 4 cell-range segments per image (256 hash blocks) so the
// per-block hash critical path (inserts) drops 4x. Global row-major match
// order == (image, segment, cell) lexicographic, so prefix over the 256
// segment counts reproduces the reference compaction order exactly.
#define AD 8
#define BD 8
#define NP 2048
#define MPTS (AD*BD*NP)            // 131072 points
#define NIMG (AD*BD)               // 64 images
#define NSPI 4                     // segments per image (cell-range split)
#define NSEG (NIMG*NSPI)           // 256 segments
#define HSZ 4096                   // LDS hash slots (worst case 4096 keys/segment)
#define RCAP 2048                  // max matches/segment (<= src cells <= 2048)
#define DPAD 65536                 // dynamic pad coverage: 256 blk x 256 thr rows

// Fully rewritten every call (no cross-call invariants).
__device__ int g_cnt[NSEG];
__device__ int g_rc[NSEG*RCAP];    // local cell index — rank key within segment
__device__ int g_rs[NSEG*RCAP];    // global src point id
__device__ int g_rd[NSEG*RCAP];    // global dst point id

// ---- k1: 256 hash blocks (img = b>>2, quarter = b&3) + 64 static-fill blocks ----
__global__ __launch_bounds__(256) void k_hash(
    const float* __restrict__ ps, const float* __restrict__ pd,
    float* __restrict__ out,
    const int* __restrict__ ph, const int* __restrict__ pw,
    const int* __restrict__ pg) {
  __shared__ int hkey[HSZ];
  __shared__ int hsrc[HSZ];
  __shared__ int hdst[HSZ];
  __shared__ int lcnt;

  int b = blockIdx.x, tid = threadIdx.x;

  if (b >= NSEG) {
    // ---- static pad rows [DPAD, M): 4 arrays x 32768 f4 + valid 16384 f4
    // = 147456 float4 = 64 blocks x 2304 = 9/thread ----
    const float4 z4  = make_float4(0.f, 0.f, 0.f, 0.f);
    const float4 m14 = make_float4(-1.f, -1.f, -1.f, -1.f);
    float4* o4 = (float4*)out;
    int pb = b - NSEG;                       // 0..63
#pragma unroll
    for (int k = 0; k < 9; ++k) {
      int q4 = pb*2304 + k*256 + tid;
      if (q4 < 131072) {
        int arr = q4 >> 15, idx = q4 & 32767;
        o4[arr*(MPTS/2) + DPAD/2 + idx] = (arr < 2) ? z4 : m14;
      } else {
        o4[2*MPTS + DPAD/4 + (q4 - 131072)] = z4;   // valid (f4 base 8*MPTS/4)
      }
    }
    return;
  }

  int img = b >> 2, seg = b & (NSPI - 1);

  for (int i = tid; i < HSZ; i += 256) { hkey[i] = -1; hsrc[i] = 0; hdst[i] = 0; }
  if (tid == 0) lcnt = 0;
  __syncthreads();

  int h = *ph, w = *pw, gs = *pg;
  int gh = h * gs, gw = w * gs;
  float sx = (float)((gw - 1) * 0.5);
  float sy = (float)((gh - 1) * 0.5);
  int ncell = gw * gh;
  int Q = (ncell + NSPI - 1) / NSPI;
  int clo = seg * Q;
  int chi = min(clo + Q, ncell);

  auto insert = [&](float px, float py, int gid, int* field) {
    if (!(px >= -1.f && px <= 1.f && py >= -1.f && py <= 1.f)) return;
    int c = (int)((px + 1.f) * sx) * gh + (int)((py + 1.f) * sy);  // local row-major
    if (c < clo || c >= chi) return;          // not this segment's cell range
    int i = (int)(((unsigned)c * 2654435761u) >> 20) & (HSZ - 1);
    while (true) {
      int k = atomicCAS(&hkey[i], -1, c);
      if (k == -1 || k == c) { atomicMax(&field[i], gid + 1); return; }
      i = (i + 1) & (HSZ - 1);
    }
  };

  const float4* sp = (const float4*)ps + img * (NP/2);
  const float4* dp = (const float4*)pd + img * (NP/2);
  int gbase = img * NP;
#pragma unroll
  for (int k = 0; k < NP/512; ++k) {          // 4 x 256 float4 = 2048 pts/side
    int f = k*256 + tid;
    float4 s2 = sp[f];
    insert(s2.x, s2.y, gbase + 2*f,     hsrc);
    insert(s2.z, s2.w, gbase + 2*f + 1, hsrc);
    float4 d2 = dp[f];
    insert(d2.x, d2.y, gbase + 2*f,     hdst);
    insert(d2.z, d2.w, gbase + 2*f + 1, hdst);
  }
  __syncthreads();

  // cells holding both a src and a dst winner -> record
  for (int i = tid; i < HSZ; i += 256) {
    if (hkey[i] >= 0) {
      int s = hsrc[i], d = hdst[i];
      if (s > 0 && d > 0) {
        int slot = atomicAdd(&lcnt, 1);
        g_rc[b*RCAP + slot] = hkey[i];
        g_rs[b*RCAP + slot] = s - 1;
        g_rd[b*RCAP + slot] = d - 1;
      }
    }
  }
  __syncthreads();
  if (tid == 0) g_cnt[b] = lcnt;
}

// ---- k2: 256 blocks; prefix 256 counts, emit own segment, pad [n, n+65536) ----
__global__ __launch_bounds__(256) void k_emit(
    const float* __restrict__ ps, const float* __restrict__ pd,
    float* __restrict__ out,
    const int* __restrict__ ph, const int* __restrict__ pw,
    const int* __restrict__ pg) {
  __shared__ int ssum[NSEG];
  int b = blockIdx.x, tid = threadIdx.x;
  int myc = g_cnt[tid];                       // plain loads (boundary-coherent)
  ssum[tid] = myc;
  // Hillis-Steele inclusive scan over 256 entries
  for (int off = 1; off < NSEG; off <<= 1) {
    __syncthreads();
    int t = (tid >= off) ? ssum[tid - off] : 0;
    __syncthreads();
    ssum[tid] += t;
  }
  __syncthreads();

  int cnt = g_cnt[b];
  int soff = ssum[b] - cnt;
  int n = ssum[NSEG - 1];

  int h = *ph, w = *pw, gs = *pg;
  int gh = h * gs, gw = w * gs;
  float sx = (float)((gw - 1) * 0.5);
  float sy = (float)((gh - 1) * 0.5);
  float fxm = (float)((double)(h - 1) / (double)(gh - 1));  // pairs with x (faithful)
  float fym = (float)((double)(w - 1) / (double)(gw - 1));

  float* out0 = out;               // src_coord_m [M,2]
  float* out1 = out + 2*MPTS;      // dst_coord_m [M,2]
  float* out2 = out + 4*MPTS;      // src_bn      [M,2]
  float* out3 = out + 6*MPTS;      // dst_an      [M,2]
  float* out4 = out + 8*MPTS;      // valid       [M]

  for (int j = tid; j < cnt; j += 256) {
    int ci = g_rc[b*RCAP + j];
    int rank = soff;
    for (int i = 0; i < cnt; ++i) rank += (int)(g_rc[b*RCAP + i] < ci);  // cells unique
    int s = g_rs[b*RCAP + j], d = g_rd[b*RCAP + j];
    float2 a2 = ((const float2*)ps)[s];
    out0[2*rank]   = (a2.x + 1.f) * sx * fxm;
    out0[2*rank+1] = (a2.y + 1.f) * sy * fym;
    float2 b2 = ((const float2*)pd)[d];
    out1[2*rank]   = (b2.x + 1.f) * sx * fxm;
    out1[2*rank+1] = (b2.y + 1.f) * sy * fym;
    out2[2*rank]   = (float)((s / NP) % BD);
    out2[2*rank+1] = (float)(s % NP);
    out3[2*rank]   = (float)(d / (BD * NP));
    out3[2*rank+1] = (float)(d % NP);
    out4[rank]     = 1.f;
  }

  // dynamic pad: row n + b*256 + tid (covers [n, n+65536); [DPAD, M) is static,
  // overlap rewrites identical values after k1 -> harmless)
  int rr = n + b*256 + tid;
  if (rr < MPTS) {
    float2* o2 = (float2*)out;
    o2[rr]          = make_float2(0.f, 0.f);
    o2[MPTS + rr]   = make_float2(0.f, 0.f);
    o2[2*MPTS + rr] = make_float2(-1.f, -1.f);
    o2[3*MPTS + rr] = make_float2(-1.f, -1.f);
    out[8*MPTS + rr] = 0.f;
  }
}

extern "C" void kernel_launch(void* const* d_in, const int* in_sizes, int n_in,
                              void* d_out, int out_size, void* d_ws, size_t ws_size,
                              hipStream_t stream) {
  const float* ps = (const float*)d_in[0];
  const float* pd = (const float*)d_in[1];
  const int* ph = (const int*)d_in[2];
  const int* pw = (const int*)d_in[3];
  const int* pg = (const int*)d_in[4];
  float* out = (float*)d_out;

  k_hash<<<NSEG + 64, 256, 0, stream>>>(ps, pd, out, ph, pw, pg);
  k_emit<<<NSEG,      256, 0, stream>>>(ps, pd, out, ph, pw, pg);
}

// Round 13
// 16.167 us; speedup vs baseline: 2.6791x; 1.0429x over previous
//
#include <hip/hip_runtime.h>

// GridMatch: A=8, B=8, N=2048, grid 640x480 per (a,b) image.
// k1: 512 pure-hash blocks (8 cell-range segments per image).
// k2: 512 blocks x 512 threads: shuffle-scan 512 counts, emit own segment,
//     pad row n+b*512+tid (covers [n, M) entirely -> no static fill).
// Global match order == (image, segment, cell) lex == reference row-major.
#define AD 8
#define BD 8
#define NP 2048
#define MPTS (AD*BD*NP)            // 131072 points
#define NIMG (AD*BD)               // 64 images
#define NSPI 8                     // segments per image (cell-range split)
#define NSEG (NIMG*NSPI)           // 512 segments
#define HSZ 4096                   // LDS hash slots (worst case 4096 keys/segment)
#define RCAP 2048                  // max matches/segment (<= src cells <= 2048)

// Fully rewritten every call (no cross-call invariants).
__device__ int g_cnt[NSEG];
__device__ int g_rc[NSEG*RCAP];    // local cell index — rank key within segment
__device__ int g_rs[NSEG*RCAP];    // global src point id
__device__ int g_rd[NSEG*RCAP];    // global dst point id

// ---- k1: 512 hash blocks (img = b>>3, segment = b&7); pure hash, no fill ----
__global__ __launch_bounds__(256) void k_hash(
    const float* __restrict__ ps, const float* __restrict__ pd,
    const int* __restrict__ ph, const int* __restrict__ pw,
    const int* __restrict__ pg) {
  __shared__ int hkey[HSZ];
  __shared__ int hsrc[HSZ];
  __shared__ int hdst[HSZ];
  __shared__ int lcnt;

  int b = blockIdx.x, tid = threadIdx.x;
  int img = b >> 3, seg = b & (NSPI - 1);

  for (int i = tid; i < HSZ; i += 256) { hkey[i] = -1; hsrc[i] = 0; hdst[i] = 0; }
  if (tid == 0) lcnt = 0;
  __syncthreads();

  int h = *ph, w = *pw, gs = *pg;
  int gh = h * gs, gw = w * gs;
  float sx = (float)((gw - 1) * 0.5);
  float sy = (float)((gh - 1) * 0.5);
  int ncell = gw * gh;
  int Q = (ncell + NSPI - 1) / NSPI;
  int clo = seg * Q;
  int chi = min(clo + Q, ncell);

  auto insert = [&](float px, float py, int gid, int* field) {
    if (!(px >= -1.f && px <= 1.f && py >= -1.f && py <= 1.f)) return;
    int c = (int)((px + 1.f) * sx) * gh + (int)((py + 1.f) * sy);  // local row-major
    if (c < clo || c >= chi) return;          // not this segment's cell range
    int i = (int)(((unsigned)c * 2654435761u) >> 20) & (HSZ - 1);
    while (true) {
      int k = atomicCAS(&hkey[i], -1, c);
      if (k == -1 || k == c) { atomicMax(&field[i], gid + 1); return; }
      i = (i + 1) & (HSZ - 1);
    }
  };

  const float4* sp = (const float4*)ps + img * (NP/2);
  const float4* dp = (const float4*)pd + img * (NP/2);
  int gbase = img * NP;
#pragma unroll
  for (int k = 0; k < NP/512; ++k) {          // 4 x 256 float4 = 2048 pts/side
    int f = k*256 + tid;
    float4 s2 = sp[f];
    insert(s2.x, s2.y, gbase + 2*f,     hsrc);
    insert(s2.z, s2.w, gbase + 2*f + 1, hsrc);
    float4 d2 = dp[f];
    insert(d2.x, d2.y, gbase + 2*f,     hdst);
    insert(d2.z, d2.w, gbase + 2*f + 1, hdst);
  }
  __syncthreads();

  // cells holding both a src and a dst winner -> record
  for (int i = tid; i < HSZ; i += 256) {
    if (hkey[i] >= 0) {
      int s = hsrc[i], d = hdst[i];
      if (s > 0 && d > 0) {
        int slot = atomicAdd(&lcnt, 1);
        g_rc[b*RCAP + slot] = hkey[i];
        g_rs[b*RCAP + slot] = s - 1;
        g_rd[b*RCAP + slot] = d - 1;
      }
    }
  }
  __syncthreads();
  if (tid == 0) g_cnt[b] = lcnt;
}

// ---- k2: 512 blocks x 512 thr; wave-shuffle scan, emit segment, pad [n, M) ----
__global__ __launch_bounds__(512) void k_emit(
    const float* __restrict__ ps, const float* __restrict__ pd,
    float* __restrict__ out,
    const int* __restrict__ ph, const int* __restrict__ pw,
    const int* __restrict__ pg) {
  __shared__ int ssum[NSEG];
  __shared__ int wsum[8];
  int b = blockIdx.x, tid = threadIdx.x;      // tid 0..511
  int lane = tid & 63, wv = tid >> 6;

  // inclusive scan of g_cnt[0..511]: wave shuffle scan + 8-wave combine
  int x = g_cnt[tid];                          // plain load (boundary-coherent)
  for (int off = 1; off < 64; off <<= 1) {
    int t = __shfl_up(x, off, 64);
    if (lane >= off) x += t;
  }
  if (lane == 63) wsum[wv] = x;
  __syncthreads();
  if (tid < 8) {
    int t = wsum[tid];
    for (int off = 1; off < 8; off <<= 1) {
      int u = __shfl_up(t, off, 8);
      if (tid >= off) t += u;
    }
    wsum[tid] = t;
  }
  __syncthreads();
  ssum[tid] = x + (wv ? wsum[wv - 1] : 0);
  __syncthreads();

  int soff = b ? ssum[b - 1] : 0;
  int cnt  = ssum[b] - soff;
  int n    = ssum[NSEG - 1];

  int h = *ph, w = *pw, gs = *pg;
  int gh = h * gs, gw = w * gs;
  float sx = (float)((gw - 1) * 0.5);
  float sy = (float)((gh - 1) * 0.5);
  float fxm = (float)((double)(h - 1) / (double)(gh - 1));  // pairs with x (faithful)
  float fym = (float)((double)(w - 1) / (double)(gw - 1));

  float* out0 = out;               // src_coord_m [M,2]
  float* out1 = out + 2*MPTS;      // dst_coord_m [M,2]
  float* out2 = out + 4*MPTS;      // src_bn      [M,2]
  float* out3 = out + 6*MPTS;      // dst_an      [M,2]
  float* out4 = out + 8*MPTS;      // valid       [M]

  for (int j = tid; j < cnt; j += 512) {
    int ci = g_rc[b*RCAP + j];
    int rank = soff;
    for (int i = 0; i < cnt; ++i) rank += (int)(g_rc[b*RCAP + i] < ci);  // cells unique
    int s = g_rs[b*RCAP + j], d = g_rd[b*RCAP + j];
    float2 a2 = ((const float2*)ps)[s];
    out0[2*rank]   = (a2.x + 1.f) * sx * fxm;
    out0[2*rank+1] = (a2.y + 1.f) * sy * fym;
    float2 b2 = ((const float2*)pd)[d];
    out1[2*rank]   = (b2.x + 1.f) * sx * fxm;
    out1[2*rank+1] = (b2.y + 1.f) * sy * fym;
    out2[2*rank]   = (float)((s / NP) % BD);
    out2[2*rank+1] = (float)(s % NP);
    out3[2*rank]   = (float)(d / (BD * NP));
    out3[2*rank+1] = (float)(d % NP);
    out4[rank]     = 1.f;
  }

  // padding: row n + b*512 + tid; 512x512 = 262144 >= M rows past n covered
  // exactly once; rows < n untouched (emit-only). Covers [n, M) completely.
  int rr = n + b*512 + tid;
  if (rr < MPTS) {
    float2* o2 = (float2*)out;
    o2[rr]          = make_float2(0.f, 0.f);
    o2[MPTS + rr]   = make_float2(0.f, 0.f);
    o2[2*MPTS + rr] = make_float2(-1.f, -1.f);
    o2[3*MPTS + rr] = make_float2(-1.f, -1.f);
    out[8*MPTS + rr] = 0.f;
  }
}

extern "C" void kernel_launch(void* const* d_in, const int* in_sizes, int n_in,
                              void* d_out, int out_size, void* d_ws, size_t ws_size,
                              hipStream_t stream) {
  const float* ps = (const float*)d_in[0];
  const float* pd = (const float*)d_in[1];
  const int* ph = (const int*)d_in[2];
  const int* pw = (const int*)d_in[3];
  const int* pg = (const int*)d_in[4];
  float* out = (float*)d_out;

  k_hash<<<NSEG, 256, 0, stream>>>(ps, pd, ph, pw, pg);
  k_emit<<<NSEG, 512, 0, stream>>>(ps, pd, out, ph, pw, pg);
}